// Round 7
// baseline (425.428 us; speedup 1.0000x reference)
//
#include <hip/hip_runtime.h>
#include <hip/hip_bf16.h>
#include <stdint.h>

#define M_DIM 4096
#define N_DIM 11008
#define K_DIM 4096

typedef float f32x4 __attribute__((ext_vector_type(4)));
typedef __bf16 bf16x8 __attribute__((ext_vector_type(8)));
typedef unsigned short u16x8 __attribute__((ext_vector_type(8)));
typedef unsigned short u16x4 __attribute__((ext_vector_type(4)));

typedef __attribute__((address_space(1))) const unsigned int guint;
typedef __attribute__((address_space(3))) unsigned int luint;
#define GLOAD_LDS16(g, l) \
    __builtin_amdgcn_global_load_lds((guint*)(g), (luint*)(l), 16, 0, 0)

#define WAIT_VM8() asm volatile("s_waitcnt vmcnt(8)" ::: "memory")
#define WAIT_VM4() asm volatile("s_waitcnt vmcnt(4)" ::: "memory")
#define WAIT_VM0() asm volatile("s_waitcnt vmcnt(0)" ::: "memory")
#define BAR()  { __builtin_amdgcn_s_barrier(); __builtin_amdgcn_sched_barrier(0); }

__device__ __forceinline__ unsigned short f2bf(float f) {
    union { float f; unsigned u; } v; v.f = f;
    return (unsigned short)((v.u + 0x7FFFu + ((v.u >> 16) & 1u)) >> 16);
}

// ---------------- Pass 1a: X f32 -> bf16 ----------------
__global__ void __launch_bounds__(256) cvt_x_kernel(
    const float* __restrict__ X, __hip_bfloat16* __restrict__ Y)
{
    const size_t i = ((size_t)blockIdx.x * 256 + threadIdx.x) * 8;
    f32x4 a = *reinterpret_cast<const f32x4*>(X + i);
    f32x4 b = *reinterpret_cast<const f32x4*>(X + i + 4);
    bf16x8 h;
    #pragma unroll
    for (int e = 0; e < 4; ++e) { h[e] = (__bf16)a[e]; h[e + 4] = (__bf16)b[e]; }
    *reinterpret_cast<bf16x8*>(Y + i) = h;
}

// ---------------- Pass 1b: GPTQ int4 -> Wt[n][k] bf16 ----------------
__global__ void __launch_bounds__(256) dequant_kernel(
    const int* __restrict__ QW, const int* __restrict__ QZ,
    const float* __restrict__ SC, __hip_bfloat16* __restrict__ Wt)
{
    const int n   = blockIdx.x * 64 + (threadIdx.x & 63);
    const int k64 = blockIdx.y * 4 + (threadIdx.x >> 6);
    const int g   = k64 >> 1;
    const int zp  = ((unsigned)QZ[g * (N_DIM / 8) + (n >> 3)] >> ((n & 7) << 2)) & 15;
    const float sc = SC[g * N_DIM + n];
    const float zs = (float)zp * sc;
    #pragma unroll
    for (int r = 0; r < 8; ++r) {
        const unsigned qw = (unsigned)QW[(size_t)(k64 * 8 + r) * N_DIM + n];
        bf16x8 h;
        #pragma unroll
        for (int j = 0; j < 8; ++j)
            h[j] = (__bf16)((float)((qw >> (j * 4)) & 15u) * sc - zs);
        *reinterpret_cast<bf16x8*>(Wt + (size_t)n * K_DIM + k64 * 64 + r * 8) = h;
    }
}

// ---------------- Pass 2: 256x256 bf16 GEMM, 8-phase schedule ----------------
// 512 thr (8 waves 2Mx4N, per-wave 128x64), BK=64, 2-buffer LDS (2x64KB).
// Per buffer, 4 K-split 16KB halves: A-kk0 @0, A-kk1 @16384, B-kk0 @32768,
// B-kk1 @49152. 4 phases/K-tile: ph0/ph1 = kk0 x {fr0-3, fr4-7}, ph2/ph3 = kk1.
// Stage order (one half/phase, 2 gloads): A-kk0, B-kk0, A-kk1, B-kk1 of tile
// t+1 during tile t. vmcnt(4) at ph1 & ph3: in-order retirement guarantees the
// two halves consumed 2 phases later are complete; barrier gives cross-wave
// visibility. Swizzle: within each 128B row-pair, slot' = ((row&1)*4+lhi) ^
// ((row>>1)&7) -> 2-way bank aliasing (free); inverse applied on gload source.
// NOTE: launch_bounds must stay (512,2) -- (512,4) spills acc (round 5).
__global__ void __launch_bounds__(512, 2) gemm_bf16_kernel(
    const __hip_bfloat16* __restrict__ A,   // [4096][4096] (m,k)
    const __hip_bfloat16* __restrict__ Bt,  // [11008][4096] (n,k)
    const float* __restrict__ BIAS, float* __restrict__ OUT)
{
    extern __shared__ unsigned char lds[];  // 131072

    const int tid  = threadIdx.x;
    const int wave = tid >> 6;
    const int lane = tid & 63;
    const int l15  = lane & 15;
    const int lhi  = lane >> 4;
    const int wr   = wave >> 2;   // 0..1 (M, 128-row strips)
    const int wc   = wave & 3;    // 0..3 (N, 64-col strips)

    // XCD-bijective swizzle: 688 blocks = 8 XCDs x 86, M-fastest within chunk
    const int bid = blockIdx.x;
    const int swz = (bid & 7) * 86 + (bid >> 3);
    const int m0  = (swz & 15) * 256;
    const int n0  = (swz >> 4) * 256;

    // ---- staging geometry (per-thread consts) ----
    // dest byte d = tid*16 (+8192): pair pp = d>>7, slot sl = (d>>4)&7
    // orig slot so = sl ^ (pp&7); row = pp*2 + (so>>2); k-off = (so&3)*8
    const int pp  = tid >> 3;
    const int so  = (tid & 7) ^ (pp & 7);
    const int grow = pp * 2 + (so >> 2);          // 0..127 (+128 for 2nd gload)
    const int klo  = (so & 3) * 8;                // 0/8/16/24
    const __hip_bfloat16* Asrc = A  + (size_t)(m0 + grow) * K_DIM + klo;
    const __hip_bfloat16* Bsrc = Bt + (size_t)(n0 + grow) * K_DIM + klo;
    const int t16 = tid * 16;

    // ---- fragment-read offsets ----
    // byte(row,lhi) = (row>>1)*128 + (((row&1)*4+lhi) ^ ((row>>1)&7))*16
    const int sws   = (((l15 & 1) << 2) | lhi) ^ ((l15 >> 1) & 7);
    const int lbase = (l15 >> 1) * 128 + sws * 16;
    int aoff[8], boff[4];
    #pragma unroll
    for (int fr = 0; fr < 8; ++fr)
        aoff[fr] = (wr * 128 + fr * 16) * 64 + lbase;
    #pragma unroll
    for (int fc = 0; fc < 4; ++fc)
        boff[fc] = (wc * 64 + fc * 16) * 64 + lbase;

    f32x4 acc[8][4] = {};

    // stage one 16KB half of tile c into buffer (c&1): 2 gloads
    auto stA0 = [&](int c) {
        const int sb = (c & 1) * 65536; const size_t k = (size_t)c * 64;
        GLOAD_LDS16(Asrc + k,                        lds + sb + t16);
        GLOAD_LDS16(Asrc + k + (size_t)128 * K_DIM,  lds + sb + 8192 + t16);
    };
    auto stB0 = [&](int c) {
        const int sb = (c & 1) * 65536; const size_t k = (size_t)c * 64;
        GLOAD_LDS16(Bsrc + k,                        lds + sb + 32768 + t16);
        GLOAD_LDS16(Bsrc + k + (size_t)128 * K_DIM,  lds + sb + 32768 + 8192 + t16);
    };
    auto stA1 = [&](int c) {
        const int sb = (c & 1) * 65536; const size_t k = (size_t)c * 64 + 32;
        GLOAD_LDS16(Asrc + k,                        lds + sb + 16384 + t16);
        GLOAD_LDS16(Asrc + k + (size_t)128 * K_DIM,  lds + sb + 16384 + 8192 + t16);
    };
    auto stB1 = [&](int c) {
        const int sb = (c & 1) * 65536; const size_t k = (size_t)c * 64 + 32;
        GLOAD_LDS16(Bsrc + k,                        lds + sb + 49152 + t16);
        GLOAD_LDS16(Bsrc + k + (size_t)128 * K_DIM,  lds + sb + 49152 + 8192 + t16);
    };

    // one K-tile = 4 phases
    auto tile = [&](int c, bool st, bool tail) {
        const int buf = (c & 1) * 65536;
        bf16x8 afr[4], bfr[4];
        // ---- ph0: kk0, fr0-3 ----
        #pragma unroll
        for (int fc = 0; fc < 4; ++fc)
            bfr[fc] = *reinterpret_cast<const bf16x8*>(lds + buf + 32768 + boff[fc]);
        #pragma unroll
        for (int fr = 0; fr < 4; ++fr)
            afr[fr] = *reinterpret_cast<const bf16x8*>(lds + buf + aoff[fr]);
        if (st) stA0(c + 1);
        BAR();
        __builtin_amdgcn_s_setprio(1);
        #pragma unroll
        for (int fr = 0; fr < 4; ++fr)
            #pragma unroll
            for (int fc = 0; fc < 4; ++fc)
                acc[fr][fc] = __builtin_amdgcn_mfma_f32_16x16x32_bf16(
                    afr[fr], bfr[fc], acc[fr][fc], 0, 0, 0);
        __builtin_amdgcn_s_setprio(0);
        BAR();
        // ---- ph1: kk0, fr4-7 (bfr held) ----
        #pragma unroll
        for (int fr = 0; fr < 4; ++fr)
            afr[fr] = *reinterpret_cast<const bf16x8*>(lds + buf + aoff[fr + 4]);
        if (st) stB0(c + 1);
        if (tail) { WAIT_VM0(); } else { WAIT_VM4(); }
        BAR();
        __builtin_amdgcn_s_setprio(1);
        #pragma unroll
        for (int fr = 0; fr < 4; ++fr)
            #pragma unroll
            for (int fc = 0; fc < 4; ++fc)
                acc[fr + 4][fc] = __builtin_amdgcn_mfma_f32_16x16x32_bf16(
                    afr[fr], bfr[fc], acc[fr + 4][fc], 0, 0, 0);
        __builtin_amdgcn_s_setprio(0);
        BAR();
        // ---- ph2: kk1, fr0-3 ----
        #pragma unroll
        for (int fc = 0; fc < 4; ++fc)
            bfr[fc] = *reinterpret_cast<const bf16x8*>(lds + buf + 49152 + boff[fc]);
        #pragma unroll
        for (int fr = 0; fr < 4; ++fr)
            afr[fr] = *reinterpret_cast<const bf16x8*>(lds + buf + 16384 + aoff[fr]);
        if (st) stA1(c + 1);
        BAR();
        __builtin_amdgcn_s_setprio(1);
        #pragma unroll
        for (int fr = 0; fr < 4; ++fr)
            #pragma unroll
            for (int fc = 0; fc < 4; ++fc)
                acc[fr][fc] = __builtin_amdgcn_mfma_f32_16x16x32_bf16(
                    afr[fr], bfr[fc], acc[fr][fc], 0, 0, 0);
        __builtin_amdgcn_s_setprio(0);
        BAR();
        // ---- ph3: kk1, fr4-7 ----
        #pragma unroll
        for (int fr = 0; fr < 4; ++fr)
            afr[fr] = *reinterpret_cast<const bf16x8*>(lds + buf + 16384 + aoff[fr + 4]);
        if (st) stB1(c + 1);
        if (!tail) { WAIT_VM4(); }
        BAR();
        __builtin_amdgcn_s_setprio(1);
        #pragma unroll
        for (int fr = 0; fr < 4; ++fr)
            #pragma unroll
            for (int fc = 0; fc < 4; ++fc)
                acc[fr + 4][fc] = __builtin_amdgcn_mfma_f32_16x16x32_bf16(
                    afr[fr], bfr[fc], acc[fr + 4][fc], 0, 0, 0);
        __builtin_amdgcn_s_setprio(0);
        BAR();
    };

    // prologue: tiles 0 and 1 fully staged, halves in consumption order
    stA0(0); stB0(0); stA1(0); stB1(0);
    stA0(1); stB0(1); stA1(1); stB1(1);
    WAIT_VM8();          // tile 0 fully resident
    BAR();

    tile(0, false, false);               // tile 1 already staged
    for (int c = 1; c <= 62; ++c)
        tile(c, true, false);            // stage tile c+1
    tile(63, false, true);               // drain

    // epilogue: OUT = acc + bias
    #pragma unroll
    for (int fc = 0; fc < 4; ++fc) {
        const int n    = n0 + wc * 64 + fc * 16 + l15;
        const float bv = BIAS[n];
        #pragma unroll
        for (int fr = 0; fr < 8; ++fr) {
            const int mb = m0 + wr * 128 + fr * 16 + (lhi << 2);
            #pragma unroll
            for (int t = 0; t < 4; ++t)
                OUT[(size_t)(mb + t) * N_DIM + n] = acc[fr][fc][t] + bv;
        }
    }
}

// ---------------- Fallback: round-1 fused kernel ----------------
__global__ void __launch_bounds__(256) gptq_gemm_kernel(
    const float* __restrict__ X, const int* __restrict__ QW,
    const int* __restrict__ QZ, const float* __restrict__ SC,
    const float* __restrict__ BIAS, float* __restrict__ OUT)
{
    __shared__ __align__(16) unsigned char slds[32768];
    const int tid  = threadIdx.x;
    const int n0   = blockIdx.x * 128;
    const int m0   = blockIdx.y * 128;
    const int wave = tid >> 6;
    const int lane = tid & 63;
    const int wm   = (wave >> 1) * 64;
    const int wn   = (wave & 1) * 64;
    const int l15  = lane & 15;
    const int lhi  = lane >> 4;
    const int arow  = tid >> 4;
    const int acol4 = (tid & 15) << 2;
    const int bnl   = tid & 127;
    const int brb   = tid >> 7;
    const int col   = n0 + bnl;

    f32x4 acc[4][4] = {};
    for (int kt = 0; kt < K_DIM / 64; ++kt) {
        const int k0 = kt * 64;
        #pragma unroll
        for (int r8 = 0; r8 < 8; ++r8) {
            const int row = (r8 << 4) + arow;
            f32x4 v = *reinterpret_cast<const f32x4*>(
                X + (size_t)(m0 + row) * K_DIM + (k0 + acol4));
            u16x4 h;
            #pragma unroll
            for (int e = 0; e < 4; ++e) h[e] = f2bf(v[e]);
            const int bo = row * 128 + ((acol4 << 1) ^ ((row & 7) << 4));
            *reinterpret_cast<u16x4*>(slds + bo) = h;
        }
        {
            const int g    = k0 >> 7;
            const int zp   = (((unsigned)QZ[g * (N_DIM / 8) + (col >> 3)])
                              >> ((col & 7) << 2)) & 15;
            const float sc = SC[g * N_DIM + col];
            const float zs = (float)zp * sc;
            #pragma unroll
            for (int rb = 0; rb < 4; ++rb) {
                const int rl = (rb << 1) + brb;
                const unsigned qw =
                    (unsigned)QW[(size_t)((k0 >> 3) + rl) * N_DIM + col];
                u16x8 h;
                #pragma unroll
                for (int j = 0; j < 8; ++j) {
                    float w = (float)((qw >> (j << 2)) & 15u) * sc - zs;
                    h[j] = f2bf(w);
                }
                const int bo = 16384 + bnl * 128 + ((rl << 4) ^ ((bnl & 7) << 4));
                *reinterpret_cast<u16x8*>(slds + bo) = h;
            }
        }
        __syncthreads();
        #pragma unroll
        for (int kk = 0; kk < 2; ++kk) {
            bf16x8 afr[4], bfr[4];
            #pragma unroll
            for (int i = 0; i < 4; ++i) {
                const int row = wm + (i << 4) + l15;
                afr[i] = *reinterpret_cast<const bf16x8*>(
                    slds + row * 128 + (((kk << 6) + (lhi << 4)) ^ ((row & 7) << 4)));
            }
            #pragma unroll
            for (int j = 0; j < 4; ++j) {
                const int n = wn + (j << 4) + l15;
                bfr[j] = *reinterpret_cast<const bf16x8*>(
                    slds + 16384 + n * 128 + (((kk << 6) + (lhi << 4)) ^ ((n & 7) << 4)));
            }
            #pragma unroll
            for (int i = 0; i < 4; ++i)
                #pragma unroll
                for (int j = 0; j < 4; ++j)
                    acc[i][j] = __builtin_amdgcn_mfma_f32_16x16x32_bf16(
                        afr[i], bfr[j], acc[i][j], 0, 0, 0);
        }
        __syncthreads();
    }
    #pragma unroll
    for (int j = 0; j < 4; ++j) {
        const int n    = n0 + wn + (j << 4) + l15;
        const float bv = BIAS[n];
        #pragma unroll
        for (int i = 0; i < 4; ++i) {
            const int mb = m0 + wm + (i << 4) + (lhi << 2);
            #pragma unroll
            for (int t = 0; t < 4; ++t)
                OUT[(size_t)(mb + t) * N_DIM + n] = acc[i][j][t] + bv;
        }
    }
}

extern "C" void kernel_launch(void* const* d_in, const int* in_sizes, int n_in,
                              void* d_out, int out_size, void* d_ws, size_t ws_size,
                              hipStream_t stream) {
    const float* X  = (const float*)d_in[0];
    const int*   QW = (const int*)d_in[1];
    const int*   QZ = (const int*)d_in[2];
    const float* SC = (const float*)d_in[3];
    const float* BI = (const float*)d_in[4];
    float*      OUT = (float*)d_out;

    const size_t xbf_bytes = (size_t)M_DIM * K_DIM * 2;
    const size_t wt_bytes  = (size_t)N_DIM * K_DIM * 2;

    if (ws_size >= xbf_bytes + wt_bytes) {
        __hip_bfloat16* Xbf = (__hip_bfloat16*)d_ws;
        __hip_bfloat16* Wt  = (__hip_bfloat16*)((char*)d_ws + xbf_bytes);

        cvt_x_kernel<<<(M_DIM * K_DIM) / (256 * 8), 256, 0, stream>>>(X, Xbf);
        dequant_kernel<<<dim3(N_DIM / 64, K_DIM / 256), 256, 0, stream>>>(QW, QZ, SC, Wt);
        gemm_bf16_kernel<<<dim3((M_DIM / 256) * (N_DIM / 256)), 512, 131072, stream>>>(
            Xbf, Wt, BI, OUT);
    } else {
        gptq_gemm_kernel<<<dim3(N_DIM / 128, M_DIM / 128), 256, 0, stream>>>(
            X, QW, QZ, SC, BI, OUT);
    }
}

// Round 8
// 408.306 us; speedup vs baseline: 1.0419x; 1.0419x over previous
//
#include <hip/hip_runtime.h>
#include <hip/hip_bf16.h>
#include <stdint.h>

#define M_DIM 4096
#define N_DIM 11008
#define K_DIM 4096

typedef float f32x4 __attribute__((ext_vector_type(4)));
typedef __bf16 bf16x8 __attribute__((ext_vector_type(8)));
typedef unsigned short u16x8 __attribute__((ext_vector_type(8)));
typedef unsigned short u16x4 __attribute__((ext_vector_type(4)));

typedef __attribute__((address_space(1))) const unsigned int guint;
typedef __attribute__((address_space(3))) unsigned int luint;
#define GLOAD_LDS16(g, l) \
    __builtin_amdgcn_global_load_lds((guint*)(g), (luint*)(l), 16, 0, 0)

#define WAIT_VM8() asm volatile("s_waitcnt vmcnt(8)" ::: "memory")
#define WAIT_VM4() asm volatile("s_waitcnt vmcnt(4)" ::: "memory")
#define WAIT_VM0() asm volatile("s_waitcnt vmcnt(0)" ::: "memory")

__device__ __forceinline__ unsigned short f2bf(float f) {
    union { float f; unsigned u; } v; v.f = f;
    return (unsigned short)((v.u + 0x7FFFu + ((v.u >> 16) & 1u)) >> 16);
}

// ---------------- Pass 1a: X f32 -> bf16 ----------------
__global__ void __launch_bounds__(256) cvt_x_kernel(
    const float* __restrict__ X, __hip_bfloat16* __restrict__ Y)
{
    const size_t i = ((size_t)blockIdx.x * 256 + threadIdx.x) * 8;
    f32x4 a = *reinterpret_cast<const f32x4*>(X + i);
    f32x4 b = *reinterpret_cast<const f32x4*>(X + i + 4);
    bf16x8 h;
    #pragma unroll
    for (int e = 0; e < 4; ++e) { h[e] = (__bf16)a[e]; h[e + 4] = (__bf16)b[e]; }
    *reinterpret_cast<bf16x8*>(Y + i) = h;
}

// ---------------- Pass 1b: GPTQ int4 -> Wt[n][k] bf16 ----------------
__global__ void __launch_bounds__(256) dequant_kernel(
    const int* __restrict__ QW, const int* __restrict__ QZ,
    const float* __restrict__ SC, __hip_bfloat16* __restrict__ Wt)
{
    const int n   = blockIdx.x * 64 + (threadIdx.x & 63);
    const int k64 = blockIdx.y * 4 + (threadIdx.x >> 6);
    const int g   = k64 >> 1;
    const int zp  = ((unsigned)QZ[g * (N_DIM / 8) + (n >> 3)] >> ((n & 7) << 2)) & 15;
    const float sc = SC[g * N_DIM + n];
    const float zs = (float)zp * sc;
    #pragma unroll
    for (int r = 0; r < 8; ++r) {
        const unsigned qw = (unsigned)QW[(size_t)(k64 * 8 + r) * N_DIM + n];
        bf16x8 h;
        #pragma unroll
        for (int j = 0; j < 8; ++j)
            h[j] = (__bf16)((float)((qw >> (j * 4)) & 15u) * sc - zs);
        *reinterpret_cast<bf16x8*>(Wt + (size_t)n * K_DIM + k64 * 64 + r * 8) = h;
    }
}

// ---------------- Pass 2: 256x256 bf16 GEMM, 8-phase schedule ----------------
// 512 thr (8 waves 2Mx4N, per-wave 128x64), BK=64, 2-buffer LDS (2x64KB).
// Per buffer, 4 K-split 16KB halves: A-kk0 @0, A-kk1 @16384, B-kk0 @32768,
// B-kk1 @49152. 4 phases/K-tile, ONE barrier per phase (skew <= 1 phase;
// stage writes always target the other buffer / a region >= 2 phases from any
// laggard's reads). Counted vmcnt(4) at ph1 & ph3 (asm w/ "memory" clobber =
// the only compiler fences needed; ds_reads are compiler-visible so lgkmcnt
// is handled by the compiler). NO sched_barrier(0) anywhere (m141: pinning
// regresses). launch_bounds stays (512,2): (512,4) spills acc (round 5).
__global__ void __launch_bounds__(512, 2) gemm_bf16_kernel(
    const __hip_bfloat16* __restrict__ A,   // [4096][4096] (m,k)
    const __hip_bfloat16* __restrict__ Bt,  // [11008][4096] (n,k)
    const float* __restrict__ BIAS, float* __restrict__ OUT)
{
    extern __shared__ unsigned char lds[];  // 131072

    const int tid  = threadIdx.x;
    const int wave = tid >> 6;
    const int lane = tid & 63;
    const int l15  = lane & 15;
    const int lhi  = lane >> 4;
    const int wr   = wave >> 2;   // 0..1 (M, 128-row strips)
    const int wc   = wave & 3;    // 0..3 (N, 64-col strips)

    // XCD-bijective swizzle: 688 blocks = 8 XCDs x 86, M-fastest within chunk
    const int bid = blockIdx.x;
    const int swz = (bid & 7) * 86 + (bid >> 3);
    const int m0  = (swz & 15) * 256;
    const int n0  = (swz >> 4) * 256;

    // ---- staging geometry (per-thread consts) ----
    // dest byte d = tid*16 (+8192): pair pp = d>>7, slot sl = (d>>4)&7
    // orig slot so = sl ^ (pp&7); row = pp*2 + (so>>2); k-off = (so&3)*8
    const int pp  = tid >> 3;
    const int so  = (tid & 7) ^ (pp & 7);
    const int grow = pp * 2 + (so >> 2);          // 0..127 (+128 for 2nd gload)
    const int klo  = (so & 3) * 8;                // 0/8/16/24
    const __hip_bfloat16* Asrc = A  + (size_t)(m0 + grow) * K_DIM + klo;
    const __hip_bfloat16* Bsrc = Bt + (size_t)(n0 + grow) * K_DIM + klo;
    const int t16 = tid * 16;

    // ---- fragment-read offsets ----
    // byte(row,lhi) = (row>>1)*128 + (((row&1)*4+lhi) ^ ((row>>1)&7))*16
    const int sws   = (((l15 & 1) << 2) | lhi) ^ ((l15 >> 1) & 7);
    const int lbase = (l15 >> 1) * 128 + sws * 16;
    int aoff[8], boff[4];
    #pragma unroll
    for (int fr = 0; fr < 8; ++fr)
        aoff[fr] = (wr * 128 + fr * 16) * 64 + lbase;
    #pragma unroll
    for (int fc = 0; fc < 4; ++fc)
        boff[fc] = (wc * 64 + fc * 16) * 64 + lbase;

    f32x4 acc[8][4] = {};

    // stage one 16KB half of tile c into buffer (c&1): 2 gloads
    auto stA0 = [&](int c) {
        const int sb = (c & 1) * 65536; const size_t k = (size_t)c * 64;
        GLOAD_LDS16(Asrc + k,                        lds + sb + t16);
        GLOAD_LDS16(Asrc + k + (size_t)128 * K_DIM,  lds + sb + 8192 + t16);
    };
    auto stB0 = [&](int c) {
        const int sb = (c & 1) * 65536; const size_t k = (size_t)c * 64;
        GLOAD_LDS16(Bsrc + k,                        lds + sb + 32768 + t16);
        GLOAD_LDS16(Bsrc + k + (size_t)128 * K_DIM,  lds + sb + 32768 + 8192 + t16);
    };
    auto stA1 = [&](int c) {
        const int sb = (c & 1) * 65536; const size_t k = (size_t)c * 64 + 32;
        GLOAD_LDS16(Asrc + k,                        lds + sb + 16384 + t16);
        GLOAD_LDS16(Asrc + k + (size_t)128 * K_DIM,  lds + sb + 16384 + 8192 + t16);
    };
    auto stB1 = [&](int c) {
        const int sb = (c & 1) * 65536; const size_t k = (size_t)c * 64 + 32;
        GLOAD_LDS16(Bsrc + k,                        lds + sb + 49152 + t16);
        GLOAD_LDS16(Bsrc + k + (size_t)128 * K_DIM,  lds + sb + 49152 + 8192 + t16);
    };

    // one K-tile = 4 phases, 1 barrier each
    auto tile = [&](int c, bool st, bool tail) {
        const int buf = (c & 1) * 65536;
        bf16x8 afr[4], bfr[4];
        // ---- ph0: kk0, fr0-3 ----
        #pragma unroll
        for (int fc = 0; fc < 4; ++fc)
            bfr[fc] = *reinterpret_cast<const bf16x8*>(lds + buf + 32768 + boff[fc]);
        #pragma unroll
        for (int fr = 0; fr < 4; ++fr)
            afr[fr] = *reinterpret_cast<const bf16x8*>(lds + buf + aoff[fr]);
        if (st) stA0(c + 1);
        __builtin_amdgcn_s_barrier();
        __builtin_amdgcn_s_setprio(1);
        #pragma unroll
        for (int fr = 0; fr < 4; ++fr)
            #pragma unroll
            for (int fc = 0; fc < 4; ++fc)
                acc[fr][fc] = __builtin_amdgcn_mfma_f32_16x16x32_bf16(
                    afr[fr], bfr[fc], acc[fr][fc], 0, 0, 0);
        __builtin_amdgcn_s_setprio(0);
        // ---- ph1: kk0, fr4-7 (bfr held) ----
        #pragma unroll
        for (int fr = 0; fr < 4; ++fr)
            afr[fr] = *reinterpret_cast<const bf16x8*>(lds + buf + aoff[fr + 4]);
        if (st) stB0(c + 1);
        if (tail) { WAIT_VM0(); } else { WAIT_VM4(); }
        __builtin_amdgcn_s_barrier();
        __builtin_amdgcn_s_setprio(1);
        #pragma unroll
        for (int fr = 0; fr < 4; ++fr)
            #pragma unroll
            for (int fc = 0; fc < 4; ++fc)
                acc[fr + 4][fc] = __builtin_amdgcn_mfma_f32_16x16x32_bf16(
                    afr[fr], bfr[fc], acc[fr + 4][fc], 0, 0, 0);
        __builtin_amdgcn_s_setprio(0);
        // ---- ph2: kk1, fr0-3 ----
        #pragma unroll
        for (int fc = 0; fc < 4; ++fc)
            bfr[fc] = *reinterpret_cast<const bf16x8*>(lds + buf + 49152 + boff[fc]);
        #pragma unroll
        for (int fr = 0; fr < 4; ++fr)
            afr[fr] = *reinterpret_cast<const bf16x8*>(lds + buf + 16384 + aoff[fr]);
        if (st) stA1(c + 1);
        __builtin_amdgcn_s_barrier();
        __builtin_amdgcn_s_setprio(1);
        #pragma unroll
        for (int fr = 0; fr < 4; ++fr)
            #pragma unroll
            for (int fc = 0; fc < 4; ++fc)
                acc[fr][fc] = __builtin_amdgcn_mfma_f32_16x16x32_bf16(
                    afr[fr], bfr[fc], acc[fr][fc], 0, 0, 0);
        __builtin_amdgcn_s_setprio(0);
        // ---- ph3: kk1, fr4-7 ----
        #pragma unroll
        for (int fr = 0; fr < 4; ++fr)
            afr[fr] = *reinterpret_cast<const bf16x8*>(lds + buf + 16384 + aoff[fr + 4]);
        if (st) stB1(c + 1);
        if (!tail) { WAIT_VM4(); }
        __builtin_amdgcn_s_barrier();
        __builtin_amdgcn_s_setprio(1);
        #pragma unroll
        for (int fr = 0; fr < 4; ++fr)
            #pragma unroll
            for (int fc = 0; fc < 4; ++fc)
                acc[fr + 4][fc] = __builtin_amdgcn_mfma_f32_16x16x32_bf16(
                    afr[fr], bfr[fc], acc[fr + 4][fc], 0, 0, 0);
        __builtin_amdgcn_s_setprio(0);
    };

    // prologue: stage tile 0 only (8 loads); wait for its kk0 halves
    stA0(0); stB0(0); stA1(0); stB1(0);
    WAIT_VM4();          // A-kk0(0), B-kk0(0) resident
    __builtin_amdgcn_s_barrier();

    for (int c = 0; c <= 62; ++c)
        tile(c, true, false);            // stage tile c+1
    tile(63, false, true);               // drain

    // epilogue: OUT = acc + bias
    #pragma unroll
    for (int fc = 0; fc < 4; ++fc) {
        const int n    = n0 + wc * 64 + fc * 16 + l15;
        const float bv = BIAS[n];
        #pragma unroll
        for (int fr = 0; fr < 8; ++fr) {
            const int mb = m0 + wr * 128 + fr * 16 + (lhi << 2);
            #pragma unroll
            for (int t = 0; t < 4; ++t)
                OUT[(size_t)(mb + t) * N_DIM + n] = acc[fr][fc][t] + bv;
        }
    }
}

// ---------------- Fallback: round-1 fused kernel ----------------
__global__ void __launch_bounds__(256) gptq_gemm_kernel(
    const float* __restrict__ X, const int* __restrict__ QW,
    const int* __restrict__ QZ, const float* __restrict__ SC,
    const float* __restrict__ BIAS, float* __restrict__ OUT)
{
    __shared__ __align__(16) unsigned char slds[32768];
    const int tid  = threadIdx.x;
    const int n0   = blockIdx.x * 128;
    const int m0   = blockIdx.y * 128;
    const int wave = tid >> 6;
    const int lane = tid & 63;
    const int wm   = (wave >> 1) * 64;
    const int wn   = (wave & 1) * 64;
    const int l15  = lane & 15;
    const int lhi  = lane >> 4;
    const int arow  = tid >> 4;
    const int acol4 = (tid & 15) << 2;
    const int bnl   = tid & 127;
    const int brb   = tid >> 7;
    const int col   = n0 + bnl;

    f32x4 acc[4][4] = {};
    for (int kt = 0; kt < K_DIM / 64; ++kt) {
        const int k0 = kt * 64;
        #pragma unroll
        for (int r8 = 0; r8 < 8; ++r8) {
            const int row = (r8 << 4) + arow;
            f32x4 v = *reinterpret_cast<const f32x4*>(
                X + (size_t)(m0 + row) * K_DIM + (k0 + acol4));
            u16x4 h;
            #pragma unroll
            for (int e = 0; e < 4; ++e) h[e] = f2bf(v[e]);
            const int bo = row * 128 + ((acol4 << 1) ^ ((row & 7) << 4));
            *reinterpret_cast<u16x4*>(slds + bo) = h;
        }
        {
            const int g    = k0 >> 7;
            const int zp   = (((unsigned)QZ[g * (N_DIM / 8) + (col >> 3)])
                              >> ((col & 7) << 2)) & 15;
            const float sc = SC[g * N_DIM + col];
            const float zs = (float)zp * sc;
            #pragma unroll
            for (int rb = 0; rb < 4; ++rb) {
                const int rl = (rb << 1) + brb;
                const unsigned qw =
                    (unsigned)QW[(size_t)((k0 >> 3) + rl) * N_DIM + col];
                u16x8 h;
                #pragma unroll
                for (int j = 0; j < 8; ++j) {
                    float w = (float)((qw >> (j << 2)) & 15u) * sc - zs;
                    h[j] = f2bf(w);
                }
                const int bo = 16384 + bnl * 128 + ((rl << 4) ^ ((bnl & 7) << 4));
                *reinterpret_cast<u16x8*>(slds + bo) = h;
            }
        }
        __syncthreads();
        #pragma unroll
        for (int kk = 0; kk < 2; ++kk) {
            bf16x8 afr[4], bfr[4];
            #pragma unroll
            for (int i = 0; i < 4; ++i) {
                const int row = wm + (i << 4) + l15;
                afr[i] = *reinterpret_cast<const bf16x8*>(
                    slds + row * 128 + (((kk << 6) + (lhi << 4)) ^ ((row & 7) << 4)));
            }
            #pragma unroll
            for (int j = 0; j < 4; ++j) {
                const int n = wn + (j << 4) + l15;
                bfr[j] = *reinterpret_cast<const bf16x8*>(
                    slds + 16384 + n * 128 + (((kk << 6) + (lhi << 4)) ^ ((n & 7) << 4)));
            }
            #pragma unroll
            for (int i = 0; i < 4; ++i)
                #pragma unroll
                for (int j = 0; j < 4; ++j)
                    acc[i][j] = __builtin_amdgcn_mfma_f32_16x16x32_bf16(
                        afr[i], bfr[j], acc[i][j], 0, 0, 0);
        }
        __syncthreads();
    }
    #pragma unroll
    for (int j = 0; j < 4; ++j) {
        const int n    = n0 + wn + (j << 4) + l15;
        const float bv = BIAS[n];
        #pragma unroll
        for (int i = 0; i < 4; ++i) {
            const int mb = m0 + wm + (i << 4) + (lhi << 2);
            #pragma unroll
            for (int t = 0; t < 4; ++t)
                OUT[(size_t)(mb + t) * N_DIM + n] = acc[i][j][t] + bv;
        }
    }
}

extern "C" void kernel_launch(void* const* d_in, const int* in_sizes, int n_in,
                              void* d_out, int out_size, void* d_ws, size_t ws_size,
                              hipStream_t stream) {
    const float* X  = (const float*)d_in[0];
    const int*   QW = (const int*)d_in[1];
    const int*   QZ = (const int*)d_in[2];
    const float* SC = (const float*)d_in[3];
    const float* BI = (const float*)d_in[4];
    float*      OUT = (float*)d_out;

    const size_t xbf_bytes = (size_t)M_DIM * K_DIM * 2;
    const size_t wt_bytes  = (size_t)N_DIM * K_DIM * 2;

    if (ws_size >= xbf_bytes + wt_bytes) {
        __hip_bfloat16* Xbf = (__hip_bfloat16*)d_ws;
        __hip_bfloat16* Wt  = (__hip_bfloat16*)((char*)d_ws + xbf_bytes);

        cvt_x_kernel<<<(M_DIM * K_DIM) / (256 * 8), 256, 0, stream>>>(X, Xbf);
        dequant_kernel<<<dim3(N_DIM / 64, K_DIM / 256), 256, 0, stream>>>(QW, QZ, SC, Wt);
        gemm_bf16_kernel<<<dim3((M_DIM / 256) * (N_DIM / 256)), 512, 131072, stream>>>(
            Xbf, Wt, BI, OUT);
    } else {
        gptq_gemm_kernel<<<dim3(N_DIM / 128, M_DIM / 128), 256, 0, stream>>>(
            X, QW, QZ, SC, BI, OUT);
    }
}